// Round 2
// baseline (255.899 us; speedup 1.0000x reference)
//
#include <hip/hip_runtime.h>
#include <hip/hip_bf16.h>

using bf16 = __hip_bfloat16;
typedef short bf16x8 __attribute__((ext_vector_type(8)));
typedef float f32x4 __attribute__((ext_vector_type(4)));
typedef unsigned long long u64;

static constexpr int NA_ = 2048, NB_ = 2048;
static constexpr int H_ = 8, DH_ = 64, INNER_ = 512;
static constexpr int MROWS = 2 * NA_;  // 4096 rows for both batches

__device__ __forceinline__ unsigned short bfbits(float x) {
  bf16 h = __float2bfloat16(x);
  return __builtin_bit_cast(unsigned short, h);
}

// ---------------- LN of input feats (DIM=256), out bf16 ----------------
__global__ __launch_bounds__(256) void ln_feat_kernel(
    const float* __restrict__ fa_in, const float* __restrict__ fb_in,
    const float* __restrict__ law, const float* __restrict__ lab,
    const float* __restrict__ lbw, const float* __restrict__ lbb,
    bf16* __restrict__ fa, bf16* __restrict__ fb) {
  int row = blockIdx.x;  // 0..8191
  const float *src, *w, *bb;
  bf16* dst;
  int r;
  if (row < MROWS) { src = fa_in; w = law; bb = lab; dst = fa; r = row; }
  else             { src = fb_in; w = lbw; bb = lbb; dst = fb; r = row - MROWS; }
  int t = threadIdx.x;
  float x = src[(size_t)r * 256 + t];
  float s = x, s2 = x * x;
#pragma unroll
  for (int m = 32; m >= 1; m >>= 1) { s += __shfl_xor(s, m); s2 += __shfl_xor(s2, m); }
  __shared__ float red[8];
  if ((t & 63) == 0) { red[t >> 6] = s; red[(t >> 6) + 4] = s2; }
  __syncthreads();
  float ts  = red[0] + red[1] + red[2] + red[3];
  float ts2 = red[4] + red[5] + red[6] + red[7];
  float mean = ts * (1.0f / 256.0f);
  float var  = ts2 * (1.0f / 256.0f) - mean * mean;
  float rstd = rsqrtf(var + 1e-5f);
  dst[(size_t)r * 256 + t] = __float2bfloat16((x - mean) * rstd * w[t] + bb[t]);
}

// -------- weight convert: Wqg_t[1024][256], Wkv_t[1024][256], Wo hi/lo --------
__global__ __launch_bounds__(256) void wconv_kernel(
    const float* __restrict__ Wq, const float* __restrict__ Wk,
    const float* __restrict__ Wv, const float* __restrict__ Wg,
    const float* __restrict__ Wo,
    bf16* __restrict__ Wqgt, bf16* __restrict__ Wkvt,
    bf16* __restrict__ Woth, bf16* __restrict__ Wotl) {
  int z = blockIdx.z;
  int idx = blockIdx.x * 256 + threadIdx.x;  // 0..131071
  if (z < 4) {
    const float* W = (z == 0) ? Wq : (z == 1) ? Wk : (z == 2) ? Wv : Wg;
    bf16* Wt = (z == 0 || z == 3) ? Wqgt : Wkvt;
    int half = (z >= 2) ? ((z == 2) ? 0 : 512) : 0;  // Wv -> kv rows 512+, Wg -> qg rows 512+
    if (z == 3) half = 512;
    if (z == 2) half = 512;  // Wv goes to Wkvt rows 512..1023
    if (z == 1) half = 0;
    int kk = idx >> 9, n = idx & 511;  // K=256, N=512
    Wt[(half + n) * 256 + kk] = __float2bfloat16(W[idx]);
  } else {
    int kk = idx >> 8, n = idx & 255;  // K=512, N=256, split hi/lo
    float w = Wo[idx];
    bf16 hi = __float2bfloat16(w);
    Woth[n * 512 + kk] = hi;
    Wotl[n * 512 + kk] = __float2bfloat16(w - __bfloat162float(hi));
  }
}

// ---------------- detect mask element width (uint8 vs int32 bool) ----------------
__global__ void maskdetect_kernel(const unsigned char* __restrict__ m, int* __restrict__ flag) {
  int t = threadIdx.x;
  if (t == 0) *flag = 0;
  __syncthreads();
  // int32-encoded bools have zero bytes at offsets not divisible by 4
  if ((t & 3) != 0 && m[t] != 0) atomicOr(flag, 1);
}

// ---------------- pack mask to bits: mbits[word] bit l = mask[word*64+l] -------
__global__ __launch_bounds__(256) void maskpack_kernel(
    const void* __restrict__ maskp, const int* __restrict__ mflag,
    u64* __restrict__ mbits) {
  size_t word = (size_t)blockIdx.x * 4 + (threadIdx.x >> 6);
  int lane = threadIdx.x & 63;
  size_t e = word * 64 + lane;
  int v;
  if (*mflag != 0) v = ((const unsigned char*)maskp)[e];
  else             v = ((const int*)maskp)[e];
  u64 bal = __ballot(v != 0);
  if (lane == 0) mbits[word] = bal;
}

// ------ fused pre-GEMM: C = A[M,256] @ Wt[1024,256]^T + bias, N=1024 ----------
// cols 0..511  -> fp32 C1[M][512]
// cols 512..1023 -> VARIANT 0: bf16 C2[M][512];  VARIANT 1: vt layout
template <int VARIANT>
__global__ __launch_bounds__(256) void gemm_fused_kernel(
    const bf16* __restrict__ A, const bf16* __restrict__ Wt,
    const float* __restrict__ bias1, const float* __restrict__ bias2,
    float* __restrict__ C1, bf16* __restrict__ C2) {
  constexpr int K = 256;
  __shared__ __align__(16) bf16 As[64 * 72];
  __shared__ __align__(16) bf16 Bs[64 * 72];
  int n0 = blockIdx.x * 64, m0 = blockIdx.y * 64;
  int t = threadIdx.x, wave = t >> 6, lane = t & 63;
  int lm = lane & 15, quad = lane >> 4, q8 = quad * 8;
  int wm = (wave & 1) * 32, wn = (wave >> 1) * 32;
  f32x4 acc[2][2] = {};
  for (int k0 = 0; k0 < K; k0 += 64) {
    __syncthreads();
#pragma unroll
    for (int i = 0; i < 4; i++) {
      int id = t + 256 * i, r = id >> 4, c = id & 15;
      *(ushort4*)(&As[r * 72 + c * 4]) =
          *(const ushort4*)(A + (size_t)(m0 + r) * K + k0 + c * 4);
      *(ushort4*)(&Bs[r * 72 + c * 4]) =
          *(const ushort4*)(Wt + (size_t)(n0 + r) * K + k0 + c * 4);
    }
    __syncthreads();
#pragma unroll
    for (int kk = 0; kk < 64; kk += 32) {
      bf16x8 af[2], bf_[2];
#pragma unroll
      for (int i = 0; i < 2; i++) {
        af[i]  = *(const bf16x8*)(&As[(wm + i * 16 + lm) * 72 + kk + q8]);
        bf_[i] = *(const bf16x8*)(&Bs[(wn + i * 16 + lm) * 72 + kk + q8]);
      }
#pragma unroll
      for (int mi = 0; mi < 2; mi++)
#pragma unroll
        for (int ni = 0; ni < 2; ni++)
          acc[mi][ni] = __builtin_amdgcn_mfma_f32_16x16x32_bf16(af[mi], bf_[ni], acc[mi][ni], 0, 0, 0);
    }
  }
#pragma unroll
  for (int mi = 0; mi < 2; mi++)
#pragma unroll
    for (int ni = 0; ni < 2; ni++) {
      int n = n0 + wn + ni * 16 + lm;
      int mb = m0 + wm + mi * 16 + quad * 4;
      if (n < 512) {
        float bvv = bias1[n];
#pragma unroll
        for (int r = 0; r < 4; r++) C1[(size_t)(mb + r) * 512 + n] = acc[mi][ni][r] + bvv;
      } else {
        int nn = n - 512;
        float bvv = bias2[nn];
        if (VARIANT == 0) {
#pragma unroll
          for (int r = 0; r < 4; r++)
            C2[(size_t)(mb + r) * 512 + nn] = __float2bfloat16(acc[mi][ni][r] + bvv);
        } else {
          int bidx = mb >> 11, j = mb & 2047;
          int hh = nn >> 6, d = nn & 63;
          ushort4 pk;
          pk.x = bfbits(acc[mi][ni][0] + bvv);
          pk.y = bfbits(acc[mi][ni][1] + bvv);
          pk.z = bfbits(acc[mi][ni][2] + bvv);
          pk.w = bfbits(acc[mi][ni][3] + bvv);
          *(ushort4*)(C2 + ((size_t)((bidx * 8 + hh) * 64 + d) * 2048 + j)) = pk;
        }
      }
    }
}

// ---------------- LN over INNER=512 of q_pre/k_pre, out bf16 ----------------
__global__ __launch_bounds__(256) void qkln_kernel(
    const float* __restrict__ qpre, const float* __restrict__ kpre,
    const float* __restrict__ qw, const float* __restrict__ qb,
    const float* __restrict__ kw, const float* __restrict__ kb,
    bf16* __restrict__ qo, bf16* __restrict__ ko) {
  int row = blockIdx.x;  // 0..8191
  const float *src, *w, *bb;
  bf16* dst;
  int r;
  if (row < MROWS) { src = qpre; w = qw; bb = qb; dst = qo; r = row; }
  else             { src = kpre; w = kw; bb = kb; dst = ko; r = row - MROWS; }
  int t = threadIdx.x;
  float x0 = src[(size_t)r * 512 + t];
  float x1 = src[(size_t)r * 512 + 256 + t];
  float s = x0 + x1, s2 = x0 * x0 + x1 * x1;
#pragma unroll
  for (int m = 32; m >= 1; m >>= 1) { s += __shfl_xor(s, m); s2 += __shfl_xor(s2, m); }
  __shared__ float red[8];
  if ((t & 63) == 0) { red[t >> 6] = s; red[(t >> 6) + 4] = s2; }
  __syncthreads();
  float ts  = red[0] + red[1] + red[2] + red[3];
  float ts2 = red[4] + red[5] + red[6] + red[7];
  float mean = ts * (1.0f / 512.0f);
  float var  = ts2 * (1.0f / 512.0f) - mean * mean;
  float rstd = rsqrtf(var + 1e-5f);
  dst[(size_t)r * 512 + t]       = __float2bfloat16((x0 - mean) * rstd * w[t] + bb[t]);
  dst[(size_t)r * 512 + 256 + t] = __float2bfloat16((x1 - mean) * rstd * w[256 + t] + bb[256 + t]);
}

// ---------------- flash attention, 8 waves: waves 0-3 j-half 0, 4-7 j-half 1 ----
// intra-block LDS merge of online-softmax state; bit-packed mask; exp2 domain.
__global__ __launch_bounds__(512) void attn_kernel(
    const bf16* __restrict__ q, const bf16* __restrict__ k,
    const bf16* __restrict__ vt, const bf16* __restrict__ g,
    const u64* __restrict__ mbits,
    bf16* __restrict__ gh, bf16* __restrict__ gl) {
  __shared__ __align__(16) char smem[64512];
  bf16* Qs = (bf16*)smem;                    // 64*72 bf16 = 9216 B
  bf16* KsB = (bf16*)(smem + 9216);          // 2 * 9216 B
  bf16* VsB = (bf16*)(smem + 27648);         // 2 * 9216 B
  bf16* PsB = (bf16*)(smem + 46080);         // 8 * 16*72*2 = 18432 B
  float* Om = (float*)(smem + 9216);         // overlay on Ks: 4*16*66*4 = 16896 B
  float* Ml = (float*)(smem + 27648);        // overlay on Vs: 4*16*2*4 = 512 B

  int qt = blockIdx.x, bh = blockIdx.y;
  int bidx = bh >> 3, h = bh & 7;
  int i0 = qt * 64;
  int t = threadIdx.x, wave = t >> 6, lane = t & 63;
  int jhalf = wave >> 2, w4 = wave & 3;
  int lm = lane & 15, quad = lane >> 4, q8 = quad * 8;
  int lt = t & 255;

  // stage Q tile (64 rows x 64 dh), all 512 threads
#pragma unroll
  for (int i = 0; i < 2; i++) {
    int id = t + 512 * i, r = id >> 4, c = id & 15;
    *(ushort4*)(&Qs[r * 72 + c * 4]) =
        *(const ushort4*)(q + (size_t)(bidx * NA_ + i0 + r) * INNER_ + h * DH_ + c * 4);
  }
  __syncthreads();
  bf16x8 aq[2];
  aq[0] = *(const bf16x8*)(&Qs[(w4 * 16 + lm) * 72 + q8]);
  aq[1] = *(const bf16x8*)(&Qs[(w4 * 16 + lm) * 72 + 32 + q8]);

  f32x4 oacc[4] = {};
  float mi_[4] = {-1e30f, -1e30f, -1e30f, -1e30f};
  float li[4] = {0.f, 0.f, 0.f, 0.f};
  const float scale2 = 0.125f * 1.44269504088896f;  // into exp2 domain

  const bf16* kb = k + (size_t)(bidx * NB_) * INNER_ + h * DH_;
  const bf16* vb = vt + (size_t)(bh * DH_) * NB_;
  int mrow = i0 + w4 * 16 + quad * 4;
  bf16* Pw = PsB + wave * (16 * 72);
  bf16* Ks = KsB + jhalf * (64 * 72);
  bf16* Vs = VsB + jhalf * (64 * 72);
  // per-row mask word pointers (words of 64 j-bits)
  const u64* mrp[4];
#pragma unroll
  for (int r = 0; r < 4; r++)
    mrp[r] = mbits + ((size_t)(bidx * NA_ + mrow + r)) * (NB_ / 64) + jhalf * 16;

  for (int it = 0; it < 16; it++) {
    int j0 = jhalf * 1024 + it * 64;
    __syncthreads();
#pragma unroll
    for (int i = 0; i < 4; i++) {
      int id = lt + 256 * i, r = id >> 4, c = id & 15;
      *(ushort4*)(&Ks[r * 72 + c * 4]) =
          *(const ushort4*)(kb + (size_t)(j0 + r) * INNER_ + c * 4);
      *(ushort4*)(&Vs[r * 72 + c * 4]) =
          *(const ushort4*)(vb + (size_t)r * NB_ + j0 + c * 4);
    }
    // load mask words while staging is in flight
    unsigned int mw[4][2];
#pragma unroll
    for (int r = 0; r < 4; r++) {
      u64 w = mrp[r][it];
      mw[r][0] = (unsigned int)w;
      mw[r][1] = (unsigned int)(w >> 32);
    }
    __syncthreads();

    // S = Q K^T for this wave's 16 q-rows x 64 j
    f32x4 s[4];
#pragma unroll
    for (int nt = 0; nt < 4; nt++) {
      bf16x8 b0 = *(const bf16x8*)(&Ks[(nt * 16 + lm) * 72 + q8]);
      bf16x8 b1 = *(const bf16x8*)(&Ks[(nt * 16 + lm) * 72 + 32 + q8]);
      f32x4 a = {0.f, 0.f, 0.f, 0.f};
      a = __builtin_amdgcn_mfma_f32_16x16x32_bf16(aq[0], b0, a, 0, 0, 0);
      a = __builtin_amdgcn_mfma_f32_16x16x32_bf16(aq[1], b1, a, 0, 0, 0);
      s[nt] = a;
    }

    // scale into exp2 domain + mask from bit words
#pragma unroll
    for (int nt = 0; nt < 4; nt++) {
      int word = nt >> 1, sh = (nt & 1) * 16;
#pragma unroll
      for (int r = 0; r < 4; r++) {
        bool live = ((mw[r][word] >> (sh + lm)) & 1u) != 0;
        s[nt][r] = live ? s[nt][r] * scale2 : -1e30f;
      }
    }

    // online softmax (rows live in 16-lane groups)
    float alpha[4];
#pragma unroll
    for (int r = 0; r < 4; r++) {
      float v = fmaxf(fmaxf(s[0][r], s[1][r]), fmaxf(s[2][r], s[3][r]));
      v = fmaxf(v, __shfl_xor(v, 1));
      v = fmaxf(v, __shfl_xor(v, 2));
      v = fmaxf(v, __shfl_xor(v, 4));
      v = fmaxf(v, __shfl_xor(v, 8));
      float mn = fmaxf(mi_[r], v);
      alpha[r] = exp2f(mi_[r] - mn);
      mi_[r] = mn;
    }
#pragma unroll
    for (int nt = 0; nt < 4; nt++)
#pragma unroll
      for (int r = 0; r < 4; r++) s[nt][r] = exp2f(s[nt][r] - mi_[r]);
#pragma unroll
    for (int r = 0; r < 4; r++) {
      float v = s[0][r] + s[1][r] + s[2][r] + s[3][r];
      v += __shfl_xor(v, 1);
      v += __shfl_xor(v, 2);
      v += __shfl_xor(v, 4);
      v += __shfl_xor(v, 8);
      li[r] = li[r] * alpha[r] + v;
    }
#pragma unroll
    for (int c = 0; c < 4; c++)
#pragma unroll
      for (int r = 0; r < 4; r++) oacc[c][r] *= alpha[r];

    // P through per-wave LDS (C-layout -> A-layout), same wave: no barrier
#pragma unroll
    for (int nt = 0; nt < 4; nt++)
#pragma unroll
      for (int r = 0; r < 4; r++)
        Pw[(quad * 4 + r) * 72 + nt * 16 + lm] = __float2bfloat16(s[nt][r]);

    bf16x8 ap0 = *(const bf16x8*)(&Pw[lm * 72 + q8]);
    bf16x8 ap1 = *(const bf16x8*)(&Pw[lm * 72 + 32 + q8]);
#pragma unroll
    for (int c = 0; c < 4; c++) {
      bf16x8 v0 = *(const bf16x8*)(&Vs[(c * 16 + lm) * 72 + q8]);
      bf16x8 v1 = *(const bf16x8*)(&Vs[(c * 16 + lm) * 72 + 32 + q8]);
      oacc[c] = __builtin_amdgcn_mfma_f32_16x16x32_bf16(ap0, v0, oacc[c], 0, 0, 0);
      oacc[c] = __builtin_amdgcn_mfma_f32_16x16x32_bf16(ap1, v1, oacc[c], 0, 0, 0);
    }
  }

  // -------- intra-block merge of the two j-halves (overlay on Ks/Vs) --------
  __syncthreads();
  if (jhalf == 1) {
#pragma unroll
    for (int c = 0; c < 4; c++)
#pragma unroll
      for (int r = 0; r < 4; r++)
        Om[w4 * (16 * 66) + (quad * 4 + r) * 66 + c * 16 + lm] = oacc[c][r];
    if (lm == 0) {
#pragma unroll
      for (int r = 0; r < 4; r++) {
        Ml[(w4 * 16 + quad * 4 + r) * 2 + 0] = mi_[r];
        Ml[(w4 * 16 + quad * 4 + r) * 2 + 1] = li[r];
      }
    }
  }
  __syncthreads();
  if (jhalf == 0) {
    float a0[4], a1[4], inv[4];
#pragma unroll
    for (int r = 0; r < 4; r++) {
      float m1 = Ml[(w4 * 16 + quad * 4 + r) * 2 + 0];
      float l1 = Ml[(w4 * 16 + quad * 4 + r) * 2 + 1];
      float mn = fmaxf(mi_[r], m1);
      a0[r] = exp2f(mi_[r] - mn);
      a1[r] = exp2f(m1 - mn);
      inv[r] = 1.0f / (li[r] * a0[r] + l1 * a1[r]);
    }
#pragma unroll
    for (int c = 0; c < 4; c++) {
      int col = h * DH_ + c * 16 + lm;
#pragma unroll
      for (int r = 0; r < 4; r++) {
        float o1 = Om[w4 * (16 * 66) + (quad * 4 + r) * 66 + c * 16 + lm];
        float o = oacc[c][r] * a0[r] + o1 * a1[r];
        size_t idx = (size_t)(bidx * NA_ + mrow + r) * INNER_ + col;
        float gv = __bfloat162float(g[idx]);
        float sig = 1.0f / (1.0f + __expf(-gv));
        float val = o * inv[r] * sig;
        bf16 hi = __float2bfloat16(val);
        gh[idx] = hi;
        gl[idx] = __float2bfloat16(val - __bfloat162float(hi));
      }
    }
  }
}

// ---------------- final GEMM in split-bf16 (hi/lo), fp32 out + bias -------------
__global__ __launch_bounds__(256) void gemm_split_kernel(
    const bf16* __restrict__ Ah, const bf16* __restrict__ Al,
    const bf16* __restrict__ Bh, const bf16* __restrict__ Bl,
    const float* __restrict__ bias, float* __restrict__ C,
    int M, int N, int K) {
  __shared__ __align__(16) bf16 Ash[64 * 72];
  __shared__ __align__(16) bf16 Asl[64 * 72];
  __shared__ __align__(16) bf16 Bsh[64 * 72];
  __shared__ __align__(16) bf16 Bsl[64 * 72];
  int n0 = blockIdx.x * 64, m0 = blockIdx.y * 64;
  int t = threadIdx.x, wave = t >> 6, lane = t & 63;
  int lm = lane & 15, quad = lane >> 4, q8 = quad * 8;
  int wm = (wave & 1) * 32, wn = (wave >> 1) * 32;
  f32x4 acc[2][2] = {};
  for (int k0 = 0; k0 < K; k0 += 64) {
    __syncthreads();
#pragma unroll
    for (int i = 0; i < 4; i++) {
      int id = t + 256 * i, r = id >> 4, c = id & 15;
      size_t ga = (size_t)(m0 + r) * K + k0 + c * 4;
      size_t gb = (size_t)(n0 + r) * K + k0 + c * 4;
      *(ushort4*)(&Ash[r * 72 + c * 4]) = *(const ushort4*)(Ah + ga);
      *(ushort4*)(&Asl[r * 72 + c * 4]) = *(const ushort4*)(Al + ga);
      *(ushort4*)(&Bsh[r * 72 + c * 4]) = *(const ushort4*)(Bh + gb);
      *(ushort4*)(&Bsl[r * 72 + c * 4]) = *(const ushort4*)(Bl + gb);
    }
    __syncthreads();
#pragma unroll
    for (int kk = 0; kk < 64; kk += 32) {
      bf16x8 ah[2], al[2], bh[2], bl[2];
#pragma unroll
      for (int i = 0; i < 2; i++) {
        ah[i] = *(const bf16x8*)(&Ash[(wm + i * 16 + lm) * 72 + kk + q8]);
        al[i] = *(const bf16x8*)(&Asl[(wm + i * 16 + lm) * 72 + kk + q8]);
        bh[i] = *(const bf16x8*)(&Bsh[(wn + i * 16 + lm) * 72 + kk + q8]);
        bl[i] = *(const bf16x8*)(&Bsl[(wn + i * 16 + lm) * 72 + kk + q8]);
      }
#pragma unroll
      for (int mi = 0; mi < 2; mi++)
#pragma unroll
        for (int ni = 0; ni < 2; ni++) {
          acc[mi][ni] = __builtin_amdgcn_mfma_f32_16x16x32_bf16(ah[mi], bh[ni], acc[mi][ni], 0, 0, 0);
          acc[mi][ni] = __builtin_amdgcn_mfma_f32_16x16x32_bf16(ah[mi], bl[ni], acc[mi][ni], 0, 0, 0);
          acc[mi][ni] = __builtin_amdgcn_mfma_f32_16x16x32_bf16(al[mi], bh[ni], acc[mi][ni], 0, 0, 0);
        }
    }
  }
#pragma unroll
  for (int mi = 0; mi < 2; mi++)
#pragma unroll
    for (int ni = 0; ni < 2; ni++) {
      int n = n0 + wn + ni * 16 + lm;
      float bvv = bias[n];
      int mb = m0 + wm + mi * 16 + quad * 4;
#pragma unroll
      for (int r = 0; r < 4; r++) C[(size_t)(mb + r) * N + n] = acc[mi][ni][r] + bvv;
    }
}

extern "C" void kernel_launch(void* const* d_in, const int* in_sizes, int n_in,
                              void* d_out, int out_size, void* d_ws, size_t ws_size,
                              hipStream_t stream) {
  const float* feat_a = (const float*)d_in[0];
  const float* feat_b = (const float*)d_in[1];
  const void*  mask   = d_in[2];
  const float* Wq = (const float*)d_in[3];
  const float* bq = (const float*)d_in[4];
  const float* Wk = (const float*)d_in[5];
  const float* bk = (const float*)d_in[6];
  const float* Wv = (const float*)d_in[7];
  const float* bv = (const float*)d_in[8];
  const float* Wg = (const float*)d_in[9];
  const float* bg = (const float*)d_in[10];
  const float* Wo = (const float*)d_in[11];
  const float* bo = (const float*)d_in[12];
  const float* law = (const float*)d_in[13];
  const float* lab = (const float*)d_in[14];
  const float* lbw = (const float*)d_in[15];
  const float* lbb = (const float*)d_in[16];
  const float* qlw = (const float*)d_in[17];
  const float* qlb = (const float*)d_in[18];
  const float* klw = (const float*)d_in[19];
  const float* klb = (const float*)d_in[20];

  char* ws = (char*)d_ws;
  size_t off = 0;
  auto alloc = [&](size_t bytes) -> void* {
    void* p = ws + off;
    off += (bytes + 255) & ~(size_t)255;
    return p;
  };
  bf16* fa    = (bf16*)alloc((size_t)MROWS * 256 * 2);
  bf16* fb    = (bf16*)alloc((size_t)MROWS * 256 * 2);
  bf16* Wqgt  = (bf16*)alloc((size_t)1024 * 256 * 2);
  bf16* Wkvt  = (bf16*)alloc((size_t)1024 * 256 * 2);
  bf16* Woth  = (bf16*)alloc((size_t)131072 * 2);
  bf16* Wotl  = (bf16*)alloc((size_t)131072 * 2);
  float* qpre = (float*)alloc((size_t)MROWS * 512 * 4);
  float* kpre = (float*)alloc((size_t)MROWS * 512 * 4);
  bf16* qb_   = (bf16*)alloc((size_t)MROWS * 512 * 2);
  bf16* kb_   = (bf16*)alloc((size_t)MROWS * 512 * 2);
  bf16* vtb   = (bf16*)alloc((size_t)1024 * 2048 * 2);
  bf16* gbuf  = (bf16*)alloc((size_t)MROWS * 512 * 2);
  bf16* gh    = (bf16*)alloc((size_t)MROWS * 512 * 2);
  bf16* gl    = (bf16*)alloc((size_t)MROWS * 512 * 2);
  u64*  mbits = (u64*)alloc((size_t)131072 * 8);
  int*  mflag = (int*)alloc(256);

  ln_feat_kernel<<<2 * MROWS, 256, 0, stream>>>(feat_a, feat_b, law, lab, lbw, lbb, fa, fb);
  wconv_kernel<<<dim3(512, 1, 5), 256, 0, stream>>>(Wq, Wk, Wv, Wg, Wo, Wqgt, Wkvt, Woth, Wotl);
  maskdetect_kernel<<<1, 256, 0, stream>>>((const unsigned char*)mask, mflag);
  maskpack_kernel<<<32768, 256, 0, stream>>>(mask, mflag, mbits);
  gemm_fused_kernel<0><<<dim3(16, 64), 256, 0, stream>>>(fa, Wqgt, bq, bg, qpre, gbuf);
  gemm_fused_kernel<1><<<dim3(16, 64), 256, 0, stream>>>(fb, Wkvt, bk, bv, kpre, vtb);
  qkln_kernel<<<2 * MROWS, 256, 0, stream>>>(qpre, kpre, qlw, qlb, klw, klb, qb_, kb_);
  attn_kernel<<<dim3(32, 16), 512, 0, stream>>>(qb_, kb_, vtb, gbuf, mbits, gh, gl);
  gemm_split_kernel<<<dim3(4, 64), 256, 0, stream>>>(gh, gl, Woth, Wotl, bo, (float*)d_out, MROWS, 256, 512);
}

// Round 3
// 213.906 us; speedup vs baseline: 1.1963x; 1.1963x over previous
//
#include <hip/hip_runtime.h>
#include <hip/hip_bf16.h>

using bf16 = __hip_bfloat16;
typedef short bf16x8 __attribute__((ext_vector_type(8)));
typedef float f32x4 __attribute__((ext_vector_type(4)));
typedef unsigned long long u64;

static constexpr int NA_ = 2048, NB_ = 2048;
static constexpr int H_ = 8, DH_ = 64, INNER_ = 512;
static constexpr int MROWS = 2 * NA_;  // 4096 rows for both batches

__device__ __forceinline__ unsigned short bfbits(float x) {
  bf16 h = __float2bfloat16(x);
  return __builtin_bit_cast(unsigned short, h);
}

__device__ __forceinline__ float exp2_fast(float x) {
#if __has_builtin(__builtin_amdgcn_exp2f)
  return __builtin_amdgcn_exp2f(x);
#else
  return exp2f(x);
#endif
}

// ---------------- LN of input feats (DIM=256), out bf16 ----------------
__global__ __launch_bounds__(256) void ln_feat_kernel(
    const float* __restrict__ fa_in, const float* __restrict__ fb_in,
    const float* __restrict__ law, const float* __restrict__ lab,
    const float* __restrict__ lbw, const float* __restrict__ lbb,
    bf16* __restrict__ fa, bf16* __restrict__ fb) {
  int row = blockIdx.x;  // 0..8191
  const float *src, *w, *bb;
  bf16* dst;
  int r;
  if (row < MROWS) { src = fa_in; w = law; bb = lab; dst = fa; r = row; }
  else             { src = fb_in; w = lbw; bb = lbb; dst = fb; r = row - MROWS; }
  int t = threadIdx.x;
  float x = src[(size_t)r * 256 + t];
  float s = x, s2 = x * x;
#pragma unroll
  for (int m = 32; m >= 1; m >>= 1) { s += __shfl_xor(s, m); s2 += __shfl_xor(s2, m); }
  __shared__ float red[8];
  if ((t & 63) == 0) { red[t >> 6] = s; red[(t >> 6) + 4] = s2; }
  __syncthreads();
  float ts  = red[0] + red[1] + red[2] + red[3];
  float ts2 = red[4] + red[5] + red[6] + red[7];
  float mean = ts * (1.0f / 256.0f);
  float var  = ts2 * (1.0f / 256.0f) - mean * mean;
  float rstd = rsqrtf(var + 1e-5f);
  dst[(size_t)r * 256 + t] = __float2bfloat16((x - mean) * rstd * w[t] + bb[t]);
}

// -------- weight convert: Wqg_t[1024][256], Wkv_t[1024][256], Wo hi/lo --------
__global__ __launch_bounds__(256) void wconv_kernel(
    const float* __restrict__ Wq, const float* __restrict__ Wk,
    const float* __restrict__ Wv, const float* __restrict__ Wg,
    const float* __restrict__ Wo,
    bf16* __restrict__ Wqgt, bf16* __restrict__ Wkvt,
    bf16* __restrict__ Woth, bf16* __restrict__ Wotl) {
  int z = blockIdx.z;
  int idx = blockIdx.x * 256 + threadIdx.x;  // 0..131071
  if (z < 4) {
    const float* W = (z == 0) ? Wq : (z == 1) ? Wk : (z == 2) ? Wv : Wg;
    bf16* Wt = (z == 0 || z == 3) ? Wqgt : Wkvt;
    int half = (z == 2 || z == 3) ? 512 : 0;  // Wv/Wg go to rows 512..1023
    int kk = idx >> 9, n = idx & 511;  // K=256, N=512
    Wt[(half + n) * 256 + kk] = __float2bfloat16(W[idx]);
  } else {
    int kk = idx >> 8, n = idx & 255;  // K=512, N=256, split hi/lo
    float w = Wo[idx];
    bf16 hi = __float2bfloat16(w);
    Woth[n * 512 + kk] = hi;
    Wotl[n * 512 + kk] = __float2bfloat16(w - __bfloat162float(hi));
  }
}

// ---------------- detect mask element width (uint8 vs int32 bool) ----------------
__global__ void maskdetect_kernel(const unsigned char* __restrict__ m, int* __restrict__ flag) {
  int t = threadIdx.x;
  if (t == 0) *flag = 0;
  __syncthreads();
  if ((t & 3) != 0 && m[t] != 0) atomicOr(flag, 1);
}

// ------- pack mask to bits, grid-stride: mbits[word] bit l = mask[word*64+l] ------
__global__ __launch_bounds__(256) void maskpack_kernel(
    const void* __restrict__ maskp, const int* __restrict__ mflag,
    u64* __restrict__ mbits) {
  const bool m8 = (*mflag != 0);
  int lane = threadIdx.x & 63;
  int wid = threadIdx.x >> 6;
  const size_t NW = 131072;  // total u64 words
  for (size_t word = (size_t)blockIdx.x * 4 + wid; word < NW; word += (size_t)gridDim.x * 4) {
    size_t e = word * 64 + lane;
    int v = m8 ? (int)((const unsigned char*)maskp)[e] : ((const int*)maskp)[e];
    u64 bal = __ballot(v != 0);
    if (lane == 0) mbits[word] = bal;
  }
}

// ------ fused pre-GEMM: C = A[M,256] @ Wt[1024,256]^T + bias, N=1024 ----------
// cols 0..511  -> fp32 C1[M][512]
// cols 512..1023 -> VARIANT 0: bf16 C2[M][512];  VARIANT 1: vt layout (LDS-bounced)
template <int VARIANT>
__global__ __launch_bounds__(256) void gemm_fused_kernel(
    const bf16* __restrict__ A, const bf16* __restrict__ Wt,
    const float* __restrict__ bias1, const float* __restrict__ bias2,
    float* __restrict__ C1, bf16* __restrict__ C2) {
  constexpr int K = 256;
  __shared__ __align__(16) bf16 As[64 * 72];
  __shared__ __align__(16) bf16 Bs[64 * 72];
  int n0 = blockIdx.x * 64, m0 = blockIdx.y * 64;
  int t = threadIdx.x, wave = t >> 6, lane = t & 63;
  int lm = lane & 15, quad = lane >> 4, q8 = quad * 8;
  int wm = (wave & 1) * 32, wn = (wave >> 1) * 32;
  f32x4 acc[2][2] = {};
  for (int k0 = 0; k0 < K; k0 += 64) {
    __syncthreads();
#pragma unroll
    for (int i = 0; i < 4; i++) {
      int id = t + 256 * i, r = id >> 4, c = id & 15;
      *(ushort4*)(&As[r * 72 + c * 4]) =
          *(const ushort4*)(A + (size_t)(m0 + r) * K + k0 + c * 4);
      *(ushort4*)(&Bs[r * 72 + c * 4]) =
          *(const ushort4*)(Wt + (size_t)(n0 + r) * K + k0 + c * 4);
    }
    __syncthreads();
#pragma unroll
    for (int kk = 0; kk < 64; kk += 32) {
      bf16x8 af[2], bf_[2];
#pragma unroll
      for (int i = 0; i < 2; i++) {
        af[i]  = *(const bf16x8*)(&As[(wm + i * 16 + lm) * 72 + kk + q8]);
        bf_[i] = *(const bf16x8*)(&Bs[(wn + i * 16 + lm) * 72 + kk + q8]);
      }
#pragma unroll
      for (int mi = 0; mi < 2; mi++)
#pragma unroll
        for (int ni = 0; ni < 2; ni++)
          acc[mi][ni] = __builtin_amdgcn_mfma_f32_16x16x32_bf16(af[mi], bf_[ni], acc[mi][ni], 0, 0, 0);
    }
  }
  if (n0 < 512) {
    // fp32 half (q_pre / k_pre)
#pragma unroll
    for (int mi = 0; mi < 2; mi++)
#pragma unroll
      for (int ni = 0; ni < 2; ni++) {
        int n = n0 + wn + ni * 16 + lm;
        float bvv = bias1[n];
        int mb = m0 + wm + mi * 16 + quad * 4;
#pragma unroll
        for (int r = 0; r < 4; r++) C1[(size_t)(mb + r) * 512 + n] = acc[mi][ni][r] + bvv;
      }
  } else if (VARIANT == 0) {
    // bf16 [M][512] (gate)
#pragma unroll
    for (int mi = 0; mi < 2; mi++)
#pragma unroll
      for (int ni = 0; ni < 2; ni++) {
        int nn = n0 - 512 + wn + ni * 16 + lm;
        float bvv = bias2[nn];
        int mb = m0 + wm + mi * 16 + quad * 4;
#pragma unroll
        for (int r = 0; r < 4; r++)
          C2[(size_t)(mb + r) * 512 + nn] = __float2bfloat16(acc[mi][ni][r] + bvv);
      }
  } else {
    // vt layout [(b*8+h)*64+d][2048], coalesced via LDS bounce (reuse As)
    __syncthreads();
#pragma unroll
    for (int mi = 0; mi < 2; mi++)
#pragma unroll
      for (int ni = 0; ni < 2; ni++) {
        int d_local = wn + ni * 16 + lm;
        float bvv = bias2[n0 - 512 + d_local];
        int j_local = wm + mi * 16 + quad * 4;
#pragma unroll
        for (int r = 0; r < 4; r++)
          As[d_local * 72 + j_local + r] = __float2bfloat16(acc[mi][ni][r] + bvv);
      }
    __syncthreads();
    int bidx = m0 >> 11, j0g = m0 & 2047;
    int hh = (n0 - 512) >> 6;
    int dl = t >> 2, jc = (t & 3) * 16;
    bf16* dstrow = C2 + (size_t)((bidx * 8 + hh) * 64 + dl) * 2048 + j0g + jc;
#pragma unroll
    for (int c = 0; c < 4; c++)
      *(ushort4*)(dstrow + c * 4) = *(const ushort4*)(&As[dl * 72 + jc + c * 4]);
  }
}

// ---------------- LN over INNER=512 of q_pre/k_pre, out bf16 ----------------
__global__ __launch_bounds__(256) void qkln_kernel(
    const float* __restrict__ qpre, const float* __restrict__ kpre,
    const float* __restrict__ qw, const float* __restrict__ qb,
    const float* __restrict__ kw, const float* __restrict__ kb,
    bf16* __restrict__ qo, bf16* __restrict__ ko) {
  int row = blockIdx.x;  // 0..8191
  const float *src, *w, *bb;
  bf16* dst;
  int r;
  if (row < MROWS) { src = qpre; w = qw; bb = qb; dst = qo; r = row; }
  else             { src = kpre; w = kw; bb = kb; dst = ko; r = row - MROWS; }
  int t = threadIdx.x;
  float x0 = src[(size_t)r * 512 + t];
  float x1 = src[(size_t)r * 512 + 256 + t];
  float s = x0 + x1, s2 = x0 * x0 + x1 * x1;
#pragma unroll
  for (int m = 32; m >= 1; m >>= 1) { s += __shfl_xor(s, m); s2 += __shfl_xor(s2, m); }
  __shared__ float red[8];
  if ((t & 63) == 0) { red[t >> 6] = s; red[(t >> 6) + 4] = s2; }
  __syncthreads();
  float ts  = red[0] + red[1] + red[2] + red[3];
  float ts2 = red[4] + red[5] + red[6] + red[7];
  float mean = ts * (1.0f / 512.0f);
  float var  = ts2 * (1.0f / 512.0f) - mean * mean;
  float rstd = rsqrtf(var + 1e-5f);
  dst[(size_t)r * 512 + t]       = __float2bfloat16((x0 - mean) * rstd * w[t] + bb[t]);
  dst[(size_t)r * 512 + 256 + t] = __float2bfloat16((x1 - mean) * rstd * w[256 + t] + bb[256 + t]);
}

// ---------------- flash attention, fixed-max softmax, transposed-S layout --------
// 8 waves: waves 0-3 handle j in [0,1024), waves 4-7 j in [1024,2048); same 64 q-rows.
// St = K.Q^T -> lane holds q-row i = lane&15, j = nt*16 + quad*4 + r (regs).
// p = exp2(s*scale2 - 16); masked-dead zeroed AFTER exp (softmax shift-invariant,
// |s*scale2| < ~10 << 16 since q,k are layer-normed). No max reduction, no alpha.
__global__ __launch_bounds__(512) void attn_kernel(
    const bf16* __restrict__ q, const bf16* __restrict__ k,
    const bf16* __restrict__ vt, const bf16* __restrict__ g,
    const u64* __restrict__ mbits,
    bf16* __restrict__ gh, bf16* __restrict__ gl) {
  __shared__ __align__(16) char smem[65024];
  bf16* Qs = (bf16*)smem;                    // 64*72 bf16 = 9216 B
  bf16* KsB = (bf16*)(smem + 9216);          // 2 * 9216 B
  bf16* VsB = (bf16*)(smem + 27648);         // 2 * 9216 B
  bf16* PsB = (bf16*)(smem + 46080);         // 8 * 16*72*2 = 18432 B
  float* Om = (float*)(smem + 9216);         // overlay on Ks: 4*16*66*4 = 16896 B
  float* Lbuf = (float*)(smem + 64512);      // 2*64 floats = 512 B

  int qt = blockIdx.x, bh = blockIdx.y;
  int bidx = bh >> 3, h = bh & 7;
  int i0 = qt * 64;
  int t = threadIdx.x, wave = t >> 6, lane = t & 63;
  int jhalf = wave >> 2, w4 = wave & 3;
  int lm = lane & 15, quad = lane >> 4, q8 = quad * 8;
  int lt = t & 255;

  // stage Q tile (64 rows x 64 dh), all 512 threads
#pragma unroll
  for (int i = 0; i < 2; i++) {
    int id = t + 512 * i, r = id >> 4, c = id & 15;
    *(ushort4*)(&Qs[r * 72 + c * 4]) =
        *(const ushort4*)(q + (size_t)(bidx * NA_ + i0 + r) * INNER_ + h * DH_ + c * 4);
  }
  __syncthreads();
  // Q as B-operand: wave's 16 q-rows = w4*16 + lm
  bf16x8 bq[2];
  bq[0] = *(const bf16x8*)(&Qs[(w4 * 16 + lm) * 72 + q8]);
  bq[1] = *(const bf16x8*)(&Qs[(w4 * 16 + lm) * 72 + 32 + q8]);

  f32x4 oacc[4] = {};
  float psum = 0.f;
  const float scale2 = 0.125f * 1.44269504088896f;  // exp2 domain

  const bf16* kb = k + (size_t)(bidx * NB_) * INNER_ + h * DH_;
  const bf16* vb = vt + (size_t)(bh * DH_) * NB_;
  bf16* Pw = PsB + wave * (16 * 72);
  bf16* Ks = KsB + jhalf * (64 * 72);
  bf16* Vs = VsB + jhalf * (64 * 72);
  // per-lane mask word pointer: row i = i0 + w4*16 + lm, 32 words per row
  const u64* mrp = mbits + ((size_t)(bidx * NA_ + i0 + w4 * 16 + lm)) * (NB_ / 64) + jhalf * 16;

  for (int it = 0; it < 16; it++) {
    int j0 = jhalf * 1024 + it * 64;
    __syncthreads();
#pragma unroll
    for (int i = 0; i < 4; i++) {
      int id = lt + 256 * i, r = id >> 4, c = id & 15;
      *(ushort4*)(&Ks[r * 72 + c * 4]) =
          *(const ushort4*)(kb + (size_t)(j0 + r) * INNER_ + c * 4);
      *(ushort4*)(&Vs[r * 72 + c * 4]) =
          *(const ushort4*)(vb + (size_t)r * NB_ + j0 + c * 4);
    }
    // mask word for this lane's q-row, while staging is in flight
    u64 sm = mrp[it] >> (quad * 4);
    __syncthreads();

    // St = K.Q^T : 4 j-subtiles of 16
    f32x4 st[4];
#pragma unroll
    for (int nt = 0; nt < 4; nt++) {
      bf16x8 a0 = *(const bf16x8*)(&Ks[(nt * 16 + lm) * 72 + q8]);
      bf16x8 a1 = *(const bf16x8*)(&Ks[(nt * 16 + lm) * 72 + 32 + q8]);
      f32x4 a = {0.f, 0.f, 0.f, 0.f};
      a = __builtin_amdgcn_mfma_f32_16x16x32_bf16(a0, bq[0], a, 0, 0, 0);
      a = __builtin_amdgcn_mfma_f32_16x16x32_bf16(a1, bq[1], a, 0, 0, 0);
      st[nt] = a;
    }

    // p = exp2(s*scale2 - 16), zero dead via bit (constant-position after u64 shift)
    float pr[4][4];
#pragma unroll
    for (int nt = 0; nt < 4; nt++)
#pragma unroll
      for (int r = 0; r < 4; r++) {
        float p = exp2_fast(st[nt][r] * scale2 - 16.0f);
        unsigned live = (unsigned)(sm >> (nt * 16 + r)) & 1u;
        pr[nt][r] = live ? p : 0.0f;
      }

    // per-lane running sum (tree)
    float s0 = (pr[0][0] + pr[0][1]) + (pr[0][2] + pr[0][3]);
    float s1 = (pr[1][0] + pr[1][1]) + (pr[1][2] + pr[1][3]);
    float s2 = (pr[2][0] + pr[2][1]) + (pr[2][2] + pr[2][3]);
    float s3 = (pr[3][0] + pr[3][1]) + (pr[3][2] + pr[3][3]);
    psum += (s0 + s1) + (s2 + s3);

    // P store: row i = lm, j = nt*16 + quad*4 + r -> r contiguous: b64 writes
#pragma unroll
    for (int nt = 0; nt < 4; nt++) {
      ushort4 pk;
      pk.x = bfbits(pr[nt][0]);
      pk.y = bfbits(pr[nt][1]);
      pk.z = bfbits(pr[nt][2]);
      pk.w = bfbits(pr[nt][3]);
      *(ushort4*)(Pw + lm * 72 + nt * 16 + quad * 4) = pk;
    }

    // PV: A = P [m=i=lane&15][k=j], B = V^T [n=d][k=j] -> O[i][d]
    bf16x8 ap0 = *(const bf16x8*)(&Pw[lm * 72 + q8]);
    bf16x8 ap1 = *(const bf16x8*)(&Pw[lm * 72 + 32 + q8]);
#pragma unroll
    for (int c = 0; c < 4; c++) {
      bf16x8 v0 = *(const bf16x8*)(&Vs[(c * 16 + lm) * 72 + q8]);
      bf16x8 v1 = *(const bf16x8*)(&Vs[(c * 16 + lm) * 72 + 32 + q8]);
      oacc[c] = __builtin_amdgcn_mfma_f32_16x16x32_bf16(ap0, v0, oacc[c], 0, 0, 0);
      oacc[c] = __builtin_amdgcn_mfma_f32_16x16x32_bf16(ap1, v1, oacc[c], 0, 0, 0);
    }
  }

  // finalize row sums: reduce across quads (row i = lm)
  psum += __shfl_xor(psum, 16);
  psum += __shfl_xor(psum, 32);

  // -------- intra-block merge of the two j-halves (no max state needed) --------
  __syncthreads();
  if (quad == 0) Lbuf[jhalf * 64 + w4 * 16 + lm] = psum;
  if (jhalf == 1) {
#pragma unroll
    for (int c = 0; c < 4; c++)
#pragma unroll
      for (int r = 0; r < 4; r++)
        Om[w4 * (16 * 66) + (quad * 4 + r) * 66 + c * 16 + lm] = oacc[c][r];
  }
  __syncthreads();
  if (jhalf == 0) {
    int mrow = i0 + w4 * 16 + quad * 4;
    float inv[4];
#pragma unroll
    for (int r = 0; r < 4; r++) {
      float l = Lbuf[w4 * 16 + quad * 4 + r] + Lbuf[64 + w4 * 16 + quad * 4 + r];
      inv[r] = 1.0f / l;
    }
#pragma unroll
    for (int c = 0; c < 4; c++) {
      int col = h * DH_ + c * 16 + lm;
#pragma unroll
      for (int r = 0; r < 4; r++) {
        float o = oacc[c][r] + Om[w4 * (16 * 66) + (quad * 4 + r) * 66 + c * 16 + lm];
        size_t idx = (size_t)(bidx * NA_ + mrow + r) * INNER_ + col;
        float gv = __bfloat162float(g[idx]);
        float sig = 1.0f / (1.0f + __expf(-gv));
        float val = o * inv[r] * sig;
        bf16 hi = __float2bfloat16(val);
        gh[idx] = hi;
        gl[idx] = __float2bfloat16(val - __bfloat162float(hi));
      }
    }
  }
}

// ---------------- final GEMM in split-bf16 (hi/lo), fp32 out + bias -------------
__global__ __launch_bounds__(256) void gemm_split_kernel(
    const bf16* __restrict__ Ah, const bf16* __restrict__ Al,
    const bf16* __restrict__ Bh, const bf16* __restrict__ Bl,
    const float* __restrict__ bias, float* __restrict__ C,
    int M, int N, int K) {
  __shared__ __align__(16) bf16 Ash[64 * 72];
  __shared__ __align__(16) bf16 Asl[64 * 72];
  __shared__ __align__(16) bf16 Bsh[64 * 72];
  __shared__ __align__(16) bf16 Bsl[64 * 72];
  int n0 = blockIdx.x * 64, m0 = blockIdx.y * 64;
  int t = threadIdx.x, wave = t >> 6, lane = t & 63;
  int lm = lane & 15, quad = lane >> 4, q8 = quad * 8;
  int wm = (wave & 1) * 32, wn = (wave >> 1) * 32;
  f32x4 acc[2][2] = {};
  for (int k0 = 0; k0 < K; k0 += 64) {
    __syncthreads();
#pragma unroll
    for (int i = 0; i < 4; i++) {
      int id = t + 256 * i, r = id >> 4, c = id & 15;
      size_t ga = (size_t)(m0 + r) * K + k0 + c * 4;
      size_t gb = (size_t)(n0 + r) * K + k0 + c * 4;
      *(ushort4*)(&Ash[r * 72 + c * 4]) = *(const ushort4*)(Ah + ga);
      *(ushort4*)(&Asl[r * 72 + c * 4]) = *(const ushort4*)(Al + ga);
      *(ushort4*)(&Bsh[r * 72 + c * 4]) = *(const ushort4*)(Bh + gb);
      *(ushort4*)(&Bsl[r * 72 + c * 4]) = *(const ushort4*)(Bl + gb);
    }
    __syncthreads();
#pragma unroll
    for (int kk = 0; kk < 64; kk += 32) {
      bf16x8 ah[2], al[2], bh[2], bl[2];
#pragma unroll
      for (int i = 0; i < 2; i++) {
        ah[i] = *(const bf16x8*)(&Ash[(wm + i * 16 + lm) * 72 + kk + q8]);
        al[i] = *(const bf16x8*)(&Asl[(wm + i * 16 + lm) * 72 + kk + q8]);
        bh[i] = *(const bf16x8*)(&Bsh[(wn + i * 16 + lm) * 72 + kk + q8]);
        bl[i] = *(const bf16x8*)(&Bsl[(wn + i * 16 + lm) * 72 + kk + q8]);
      }
#pragma unroll
      for (int mi = 0; mi < 2; mi++)
#pragma unroll
        for (int ni = 0; ni < 2; ni++) {
          acc[mi][ni] = __builtin_amdgcn_mfma_f32_16x16x32_bf16(ah[mi], bh[ni], acc[mi][ni], 0, 0, 0);
          acc[mi][ni] = __builtin_amdgcn_mfma_f32_16x16x32_bf16(ah[mi], bl[ni], acc[mi][ni], 0, 0, 0);
          acc[mi][ni] = __builtin_amdgcn_mfma_f32_16x16x32_bf16(al[mi], bh[ni], acc[mi][ni], 0, 0, 0);
        }
    }
  }
#pragma unroll
  for (int mi = 0; mi < 2; mi++)
#pragma unroll
    for (int ni = 0; ni < 2; ni++) {
      int n = n0 + wn + ni * 16 + lm;
      float bvv = bias[n];
      int mb = m0 + wm + mi * 16 + quad * 4;
#pragma unroll
      for (int r = 0; r < 4; r++) C[(size_t)(mb + r) * N + n] = acc[mi][ni][r] + bvv;
    }
}

extern "C" void kernel_launch(void* const* d_in, const int* in_sizes, int n_in,
                              void* d_out, int out_size, void* d_ws, size_t ws_size,
                              hipStream_t stream) {
  const float* feat_a = (const float*)d_in[0];
  const float* feat_b = (const float*)d_in[1];
  const void*  mask   = d_in[2];
  const float* Wq = (const float*)d_in[3];
  const float* bq = (const float*)d_in[4];
  const float* Wk = (const float*)d_in[5];
  const float* bk = (const float*)d_in[6];
  const float* Wv = (const float*)d_in[7];
  const float* bv = (const float*)d_in[8];
  const float* Wg = (const float*)d_in[9];
  const float* bg = (const float*)d_in[10];
  const float* Wo = (const float*)d_in[11];
  const float* bo = (const float*)d_in[12];
  const float* law = (const float*)d_in[13];
  const float* lab = (const float*)d_in[14];
  const float* lbw = (const float*)d_in[15];
  const float* lbb = (const float*)d_in[16];
  const float* qlw = (const float*)d_in[17];
  const float* qlb = (const float*)d_in[18];
  const float* klw = (const float*)d_in[19];
  const float* klb = (const float*)d_in[20];

  char* ws = (char*)d_ws;
  size_t off = 0;
  auto alloc = [&](size_t bytes) -> void* {
    void* p = ws + off;
    off += (bytes + 255) & ~(size_t)255;
    return p;
  };
  bf16* fa    = (bf16*)alloc((size_t)MROWS * 256 * 2);
  bf16* fb    = (bf16*)alloc((size_t)MROWS * 256 * 2);
  bf16* Wqgt  = (bf16*)alloc((size_t)1024 * 256 * 2);
  bf16* Wkvt  = (bf16*)alloc((size_t)1024 * 256 * 2);
  bf16* Woth  = (bf16*)alloc((size_t)131072 * 2);
  bf16* Wotl  = (bf16*)alloc((size_t)131072 * 2);
  float* qpre = (float*)alloc((size_t)MROWS * 512 * 4);
  float* kpre = (float*)alloc((size_t)MROWS * 512 * 4);
  bf16* qb_   = (bf16*)alloc((size_t)MROWS * 512 * 2);
  bf16* kb_   = (bf16*)alloc((size_t)MROWS * 512 * 2);
  bf16* vtb   = (bf16*)alloc((size_t)1024 * 2048 * 2);
  bf16* gbuf  = (bf16*)alloc((size_t)MROWS * 512 * 2);
  bf16* gh    = (bf16*)alloc((size_t)MROWS * 512 * 2);
  bf16* gl    = (bf16*)alloc((size_t)MROWS * 512 * 2);
  u64*  mbits = (u64*)alloc((size_t)131072 * 8);
  int*  mflag = (int*)alloc(256);

  ln_feat_kernel<<<2 * MROWS, 256, 0, stream>>>(feat_a, feat_b, law, lab, lbw, lbb, fa, fb);
  wconv_kernel<<<dim3(512, 1, 5), 256, 0, stream>>>(Wq, Wk, Wv, Wg, Wo, Wqgt, Wkvt, Woth, Wotl);
  maskdetect_kernel<<<1, 256, 0, stream>>>((const unsigned char*)mask, mflag);
  maskpack_kernel<<<2048, 256, 0, stream>>>(mask, mflag, mbits);
  gemm_fused_kernel<0><<<dim3(16, 64), 256, 0, stream>>>(fa, Wqgt, bq, bg, qpre, gbuf);
  gemm_fused_kernel<1><<<dim3(16, 64), 256, 0, stream>>>(fb, Wkvt, bk, bv, kpre, vtb);
  qkln_kernel<<<2 * MROWS, 256, 0, stream>>>(qpre, kpre, qlw, qlb, klw, klb, qb_, kb_);
  attn_kernel<<<dim3(32, 16), 512, 0, stream>>>(qb_, kb_, vtb, gbuf, mbits, gh, gl);
  gemm_split_kernel<<<dim3(4, 64), 256, 0, stream>>>(gh, gl, Woth, Wotl, bo, (float*)d_out, MROWS, 256, 512);
}